// Round 7
// baseline (100.620 us; speedup 1.0000x reference)
//
#include <hip/hip_runtime.h>
#include <math.h>

// features: (1,50,50,1024) fp32 NHWC; boxes: (1,300,4) [y1,x1,y2,x2] in [0,1]
// CROP=14, POOL_K=2 -> out (1,300,7,7,1024) fp32
//
// R11: MLP attack. Elimination: not BW-bound (R8), not issue-bound (R9b),
// not chain-length-bound (R10). Last latency lever: loads-in-flight per
// wave. The rolling cache kept only ~4-8 loads outstanding and serialized
// each step through the rotate. This round: NO rolling cache -- each
// sample independently loads its NR x 2 columns; sample i+2's loads are
// issued right after computing sample i (2-deep pipeline, up to 16 loads
// in flight, each covered by 2 compute phases). ~1.65x more load instrs
// (R9b proved issue-insensitivity). Kept: bf16 ws + NT cvt, channel-
// quarter->XCD-pair partition, row dedup, NT out stores, 8400 single-wave
// blocks, launch_bounds(64,6).
#define FH 50
#define FW 50
#define FC 1024
#define FC4 256        // float4s per pixel (fp32 out) == uint2s per pixel (bf16)
#define NBOX 300
#define PO 7
#define CHQ 4
#define NPIX (FH * FW * FC)      // 2,560,000 elements
#define BF16_BYTES (NPIX * 2)    // 5,242,880

typedef float nat4 __attribute__((ext_vector_type(4)));

__device__ __forceinline__ nat4 lerp4(nat4 a, nat4 b, float w) {
    return a + (b - a) * w;
}
__device__ __forceinline__ nat4 max4(nat4 a, nat4 b) {
    nat4 r;
    r.x = fmaxf(a.x, b.x);
    r.y = fmaxf(a.y, b.y);
    r.z = fmaxf(a.z, b.z);
    r.w = fmaxf(a.w, b.w);
    return r;
}
// unpack 4 bf16 channels (packed little-endian in uint2) to f32
__device__ __forceinline__ nat4 bf2f(uint2 u) {
    nat4 r;
    r.x = __uint_as_float(u.x << 16);
    r.y = __uint_as_float(u.x & 0xffff0000u);
    r.z = __uint_as_float(u.y << 16);
    r.w = __uint_as_float(u.y & 0xffff0000u);
    return r;
}
__device__ __forceinline__ unsigned bfpack(float a, float b) {  // RNE to bf16
    unsigned ua = __float_as_uint(a);
    unsigned ub = __float_as_uint(b);
    ua += 0x7fffu + ((ua >> 16) & 1u);
    ub += 0x7fffu + ((ub >> 16) & 1u);
    return (ua >> 16) | (ub & 0xffff0000u);
}

// Pass 1: fp32 features -> bf16 in workspace (15 MB traffic, ~3 us).
// NT loads: feat is touch-once here; don't evict the ws from L2.
__global__ __launch_bounds__(256) void cvt_kernel(
    const float* __restrict__ feat, unsigned* __restrict__ ws)
{
    const int i = blockIdx.x * 256 + threadIdx.x;   // nat4 index, 640,000 total
    const nat4 v = __builtin_nontemporal_load(
        reinterpret_cast<const nat4*>(feat) + i);
    uint2 w;
    w.x = bfpack(v.x, v.y);
    w.y = bfpack(v.z, v.w);
    reinterpret_cast<uint2*>(ws)[i] = w;
}

// Per-sample independent loads, 2-deep software pipeline.
// Fully unrolled: all buffer indices are compile-time (no scratch).
template<int NR>
__device__ __forceinline__ void pool_samples(
    const uint2* __restrict__ f2, const int (&rows)[NR], int c,
    float basex, float stepx, float wyA, float wyB,
    nat4* __restrict__ obase)
{
    uint2 buf[2][NR][2];

    // Prologue: issue loads for samples 0 and 1.
#pragma unroll
    for (int p = 0; p < 2; ++p) {
        const float xs = basex + (float)p * stepx;
        const int x0 = min(max((int)floorf(xs), 0), FW - 1);
        const int x1 = min(x0 + 1, FW - 1);
#pragma unroll
        for (int q = 0; q < NR; ++q) {
            buf[p][q][0] = f2[(rows[q] + x0) * FC4 + c];
            buf[p][q][1] = f2[(rows[q] + x1) * FC4 + c];
        }
    }

    nat4 m = (nat4)(-INFINITY);
#pragma unroll
    for (int i = 0; i < 2 * PO; ++i) {
        const int sl = i & 1;               // compile-time after unroll

        // ---- Compute sample i from buf[sl] ----
        {
            const float xs = basex + (float)i * stepx;
            const float wx = xs - floorf(xs);   // unclipped floor for the weight
            nat4 a[NR];
#pragma unroll
            for (int q = 0; q < NR; ++q)
                a[q] = lerp4(bf2f(buf[sl][q][0]), bf2f(buf[sl][q][1]), wx);
            const nat4 vA = lerp4(a[0], a[1], wyA);
            nat4 vB;
            if constexpr (NR == 2)      vB = lerp4(a[0], a[1], wyB);
            else if constexpr (NR == 3) vB = lerp4(a[1], a[2], wyB);
            else                        vB = lerp4(a[2], a[3], wyB);
            m = max4(m, max4(vA, vB));
        }

        // ---- Prefetch sample i+2 into the slot just consumed ----
        if (i < 2 * PO - 2) {
            const float xs2 = basex + (float)(i + 2) * stepx;
            const int x0 = min(max((int)floorf(xs2), 0), FW - 1);
            const int x1 = min(x0 + 1, FW - 1);
#pragma unroll
            for (int q = 0; q < NR; ++q) {
                buf[sl][q][0] = f2[(rows[q] + x0) * FC4 + c];
                buf[sl][q][1] = f2[(rows[q] + x1) * FC4 + c];
            }
        }

        if (i & 1) {
            // write-once output: NT store keeps it out of L1/L2
            __builtin_nontemporal_store(m, obase + (i >> 1) * FC4);
            m = (nat4)(-INFINITY);
        }
    }
}

// Pass 2: one SINGLE-WAVE block per (box, pooled row, channel-quarter).
// blockIdx%8 (empirical XCD slot): low 2 bits carry the channel quarter,
// so quarter cq runs only on XCDs {cq, cq+4}; each XCD's L2 working set is
// one 256-channel slice = 1.28 MB (L2-resident). 8400 blocks.
__global__ __launch_bounds__(64, 6) void roi_pool_bf16_kernel(
    const unsigned* __restrict__ ws,   // bf16 features (50,50,1024)
    const float* __restrict__ boxes,   // (300,4)
    float* __restrict__ out)           // (300,7,7,1024)
{
    const int j    = blockIdx.x & 7;           // XCD slot
    const int cq   = j & 3;                    // channel quarter -> XCD pair
    const int g    = blockIdx.x >> 3;          // [0, 1050)
    const int unit = g * 2 + (j >> 2);         // [0, 2100) = (box, pooled row)
    const int n    = unit / 7;                 // box 0..299
    const int py   = unit - n * 7;             // pooled row 0..6
    const int c    = cq * 64 + threadIdx.x;    // uint2 index in pixel, 0..255

    const float by1 = boxes[n * 4 + 0];
    const float bx1 = boxes[n * 4 + 1];
    const float by2 = boxes[n * 4 + 2];
    const float bx2 = boxes[n * 4 + 3];

    const float stepy = (by2 - by1) * (49.0f / 13.0f);
    const float stepx = (bx2 - bx1) * (49.0f / 13.0f);
    const float basey = by1 * 49.0f;
    const float basex = bx1 * 49.0f;

    const float ysA = basey + (float)(2 * py) * stepy;
    const float ysB = ysA + stepy;
    const float fA = floorf(ysA); const float wyA = ysA - fA;
    const float fB = floorf(ysB); const float wyB = ysB - fB;
    const int y0A = min(max((int)fA, 0), FH - 1); const int y1A = min(y0A + 1, FH - 1);
    const int y0B = min(max((int)fB, 0), FH - 1); const int y1B = min(y0B + 1, FH - 1);

    const uint2* __restrict__ f2 = reinterpret_cast<const uint2*>(ws);
    nat4* __restrict__ obase =
        reinterpret_cast<nat4*>(out) + (size_t)(n * (PO * PO) + py * PO) * FC4 + c;

    if (y0B == y0A) {              // 2 unique rows (also covers y-clamped edge)
        const int rows[2] = {y0A * FW, y1A * FW};
        pool_samples<2>(f2, rows, c, basex, stepx, wyA, wyB, obase);
    } else if (y0B == y1A) {       // 3 unique rows, middle shared
        const int rows[3] = {y0A * FW, y1A * FW, y1B * FW};
        pool_samples<3>(f2, rows, c, basex, stepx, wyA, wyB, obase);
    } else {                       // 4 unique rows
        const int rows[4] = {y0A * FW, y1A * FW, y0B * FW, y1B * FW};
        pool_samples<4>(f2, rows, c, basex, stepx, wyA, wyB, obase);
    }
}

// Fallback (ws too small): fp32 single-wave rolling-cache kernel (R6).
__global__ __launch_bounds__(64) void roi_pool_f32_kernel(
    const float* __restrict__ feat,
    const float* __restrict__ boxes,
    float* __restrict__ out)
{
    const int j = blockIdx.x & 7;
    const int k = blockIdx.x >> 3;
    const int n = j + 8 * (k / (PO * CHQ));
    if (n >= NBOX) return;
    const int r  = k % (PO * CHQ);
    const int py = r >> 2;
    const int cq = r & 3;
    const int c4 = cq * 64 + threadIdx.x;

    const float by1 = boxes[n * 4 + 0];
    const float bx1 = boxes[n * 4 + 1];
    const float by2 = boxes[n * 4 + 2];
    const float bx2 = boxes[n * 4 + 3];
    const float stepy = (by2 - by1) * (49.0f / 13.0f);
    const float stepx = (bx2 - bx1) * (49.0f / 13.0f);
    const float basey = by1 * 49.0f;
    const float basex = bx1 * 49.0f;
    const float ysA = basey + (float)(2 * py) * stepy;
    const float ysB = ysA + stepy;
    const float fA = floorf(ysA); const float wyA = ysA - fA;
    const float fB = floorf(ysB); const float wyB = ysB - fB;
    const int y0A = min(max((int)fA, 0), FH - 1); const int y1A = min(y0A + 1, FH - 1);
    const int y0B = min(max((int)fB, 0), FH - 1); const int y1B = min(y0B + 1, FH - 1);

    const nat4* __restrict__ f4 = reinterpret_cast<const nat4*>(feat);
    const int rA0 = y0A * FW, rA1 = y1A * FW, rB0 = y0B * FW, rB1 = y1B * FW;

    int cc = -1000;
    nat4 A00, A01, A10, A11, B00, B01, B10, B11;
    A00 = A01 = A10 = A11 = B00 = B01 = B10 = B11 = (nat4)0.0f;
    nat4 m = (nat4)(-INFINITY);
    nat4* __restrict__ obase =
        reinterpret_cast<nat4*>(out) + (size_t)(n * (PO * PO) + py * PO) * FC4 + c4;

    for (int ix = 0; ix < 2 * PO; ++ix) {
        const float xs = basex + (float)ix * stepx;
        const float xf = floorf(xs);
        const float wx = xs - xf;
        int x0 = min(max((int)xf, 0), FW - 1);
        const int x1 = min(x0 + 1, FW - 1);
        if (x0 != cc) {
            if (x0 == cc + 1) {
                A00 = A01; A10 = A11; B00 = B01; B10 = B11;
                A01 = f4[(rA0 + x1) * FC4 + c4];
                A11 = f4[(rA1 + x1) * FC4 + c4];
                B01 = f4[(rB0 + x1) * FC4 + c4];
                B11 = f4[(rB1 + x1) * FC4 + c4];
            } else {
                A00 = f4[(rA0 + x0) * FC4 + c4];
                A01 = f4[(rA0 + x1) * FC4 + c4];
                A10 = f4[(rA1 + x0) * FC4 + c4];
                A11 = f4[(rA1 + x1) * FC4 + c4];
                B00 = f4[(rB0 + x0) * FC4 + c4];
                B01 = f4[(rB0 + x1) * FC4 + c4];
                B10 = f4[(rB1 + x0) * FC4 + c4];
                B11 = f4[(rB1 + x1) * FC4 + c4];
            }
            cc = x0;
        }
        const nat4 vA = lerp4(lerp4(A00, A01, wx), lerp4(A10, A11, wx), wyA);
        const nat4 vB = lerp4(lerp4(B00, B01, wx), lerp4(B10, B11, wx), wyB);
        m = max4(m, max4(vA, vB));
        if (ix & 1) {
            __builtin_nontemporal_store(m, obase + (ix >> 1) * FC4);
            m = (nat4)(-INFINITY);
        }
    }
}

extern "C" void kernel_launch(void* const* d_in, const int* in_sizes, int n_in,
                              void* d_out, int out_size, void* d_ws, size_t ws_size,
                              hipStream_t stream) {
    (void)in_sizes; (void)n_in; (void)out_size;
    const float* feat  = (const float*)d_in[0];  // (1,50,50,1024)
    const float* boxes = (const float*)d_in[1];  // (1,300,4)
    float* out = (float*)d_out;                  // (1,300,7,7,1024)

    if (ws_size >= (size_t)BF16_BYTES) {
        unsigned* wsb = (unsigned*)d_ws;
        cvt_kernel<<<dim3(NPIX / 4 / 256), dim3(256), 0, stream>>>(feat, wsb);
        // 8 XCD slots x 1050 = 8400 single-wave blocks; cq = slot & 3
        roi_pool_bf16_kernel<<<dim3(8 * 1050), dim3(64), 0, stream>>>(wsb, boxes, out);
    } else {
        roi_pool_f32_kernel<<<dim3(8 * 38 * PO * CHQ), dim3(64), 0, stream>>>(feat, boxes, out);
    }
}

// Round 8
// 96.788 us; speedup vs baseline: 1.0396x; 1.0396x over previous
//
#include <hip/hip_runtime.h>
#include <math.h>

// features: (1,50,50,1024) fp32 NHWC; boxes: (1,300,4) [y1,x1,y2,x2] in [0,1]
// CROP=14, POOL_K=2 -> out (1,300,7,7,1024) fp32
//
// R12: producer/consumer L2 alignment. Four structural attacks on the pool
// (BW, issue, chain length, MLP) were all ~null; best remains R8's rolling
// cache + reader-side channel-quarter->XCD-pair partition (96.5us). The
// untested tier: FIRST-TOUCH. The poison fill flushes caches each iter;
// linear cvt scatters ws lines across XCD L2s uncorrelated with channel,
// so the pool's first pass is all remote misses. This round cvt adopts the
// SAME slot mapping as the pool: slot j converts quarter cq=j&3 (pixel
// half j>>2), so quarter cq is produced AND consumed on XCDs {cq, cq+4}.
// Pool kernel = R8's verbatim (best measured).
#define FH 50
#define FW 50
#define FC 1024
#define FC4 256        // float4s per pixel (fp32) == uint2s per pixel (bf16)
#define NBOX 300
#define PO 7
#define CHQ 4
#define NPIX (FH * FW * FC)      // 2,560,000 elements
#define BF16_BYTES (NPIX * 2)    // 5,242,880

typedef float nat4 __attribute__((ext_vector_type(4)));

__device__ __forceinline__ nat4 lerp4(nat4 a, nat4 b, float w) {
    return a + (b - a) * w;
}
__device__ __forceinline__ nat4 max4(nat4 a, nat4 b) {
    nat4 r;
    r.x = fmaxf(a.x, b.x);
    r.y = fmaxf(a.y, b.y);
    r.z = fmaxf(a.z, b.z);
    r.w = fmaxf(a.w, b.w);
    return r;
}
// unpack 4 bf16 channels (packed little-endian in uint2) to f32
__device__ __forceinline__ nat4 bf2f(uint2 u) {
    nat4 r;
    r.x = __uint_as_float(u.x << 16);
    r.y = __uint_as_float(u.x & 0xffff0000u);
    r.z = __uint_as_float(u.y << 16);
    r.w = __uint_as_float(u.y & 0xffff0000u);
    return r;
}
__device__ __forceinline__ unsigned bfpack(float a, float b) {  // RNE to bf16
    unsigned ua = __float_as_uint(a);
    unsigned ub = __float_as_uint(b);
    ua += 0x7fffu + ((ua >> 16) & 1u);
    ub += 0x7fffu + ((ub >> 16) & 1u);
    return (ua >> 16) | (ub & 0xffff0000u);
}

// Pass 1: fp32 -> bf16 ws, XCD-ALIGNED with the pool's reader partition.
// slot j = blockIdx&7: quarter cq=j&3, pixel half h=j>>2.
// 256 threads = 4 pixel-quarters (64 lanes each, 1KB fp32 read / 512B write,
// both contiguous per wave-half... per 64-lane group).
// feat read is touch-once -> NT load; ws write NOT NT (want it L2-resident).
__global__ __launch_bounds__(256) void cvt_kernel(
    const float* __restrict__ feat, unsigned* __restrict__ ws)
{
    const int j   = blockIdx.x & 7;
    const int cq  = j & 3;
    const int h   = j >> 2;
    const int g   = blockIdx.x >> 3;          // [0, 313)
    const int sub = threadIdx.x >> 6;         // 0..3
    const int lane = threadIdx.x & 63;
    const int lp  = g * 4 + sub;              // local pixel in half, [0,1252)
    if (lp >= 1250) return;
    const int pixel = h * 1250 + lp;          // 0..2499
    const int idx = pixel * 256 + cq * 64 + lane;   // nat4/uint2 index
    const nat4 v = __builtin_nontemporal_load(
        reinterpret_cast<const nat4*>(feat) + idx);
    uint2 w;
    w.x = bfpack(v.x, v.y);
    w.y = bfpack(v.z, v.w);
    reinterpret_cast<uint2*>(ws)[idx] = w;
}

// Rolling NR x 2 bf16 column cache + 1-column software prefetch.
// All control flow wave-uniform; arrays compile-time indexed after full
// unroll -> stay in VGPRs.  (R8 verbatim -- best measured.)
template<int NR>
__device__ __forceinline__ void pool_rows(
    const uint2* __restrict__ f2, const int (&rows)[NR], int c,
    float basex, float stepx, float wyA, float wyB,
    nat4* __restrict__ obase)
{
    uint2 cur[NR][2], nxt[NR][2];
    int cc;
    {
        const float xf = floorf(basex);
        cc = min(max((int)xf, 0), FW - 1);
        const int x1 = min(cc + 1, FW - 1);
#pragma unroll
        for (int q = 0; q < NR; ++q) {
            cur[q][0] = f2[(rows[q] + cc) * FC4 + c];
            cur[q][1] = f2[(rows[q] + x1) * FC4 + c];
        }
    }

    nat4 m = (nat4)(-INFINITY);
    for (int ix = 0; ix < 2 * PO; ++ix) {
        // ---- Prefetch: issue loads for column ix+1 (no load dependence) ----
        int d = 0;
        if (ix < 2 * PO - 1) {
            const float xsn = basex + (float)(ix + 1) * stepx;
            const int nx0 = min(max((int)floorf(xsn), 0), FW - 1);
            const int nx1 = min(nx0 + 1, FW - 1);
            d = nx0 - cc;
            if (d == 1) {
#pragma unroll
                for (int q = 0; q < NR; ++q)
                    nxt[q][1] = f2[(rows[q] + nx1) * FC4 + c];
            } else if (d >= 2) {
#pragma unroll
                for (int q = 0; q < NR; ++q) {
                    nxt[q][0] = f2[(rows[q] + nx0) * FC4 + c];
                    nxt[q][1] = f2[(rows[q] + nx1) * FC4 + c];
                }
            }
            cc = nx0;
        }

        // ---- Compute sample ix from current registers ----
        {
            const float xs = basex + (float)ix * stepx;
            const float wx = xs - floorf(xs);   // unclipped floor for the weight
            nat4 a[NR];
#pragma unroll
            for (int q = 0; q < NR; ++q)
                a[q] = lerp4(bf2f(cur[q][0]), bf2f(cur[q][1]), wx);
            const nat4 vA = lerp4(a[0], a[1], wyA);
            nat4 vB;
            if constexpr (NR == 2)      vB = lerp4(a[0], a[1], wyB);
            else if constexpr (NR == 3) vB = lerp4(a[1], a[2], wyB);
            else                        vB = lerp4(a[2], a[3], wyB);
            m = max4(m, max4(vA, vB));
        }

        if (ix & 1) {
            // write-once output: NT store keeps it out of L1/L2
            __builtin_nontemporal_store(m, obase + (ix >> 1) * FC4);
            m = (nat4)(-INFINITY);
        }

        // ---- Rotate incoming -> current (wave-uniform branches) ----
        if (ix < 2 * PO - 1) {
            if (d == 1) {
#pragma unroll
                for (int q = 0; q < NR; ++q) { cur[q][0] = cur[q][1]; cur[q][1] = nxt[q][1]; }
            } else if (d >= 2) {
#pragma unroll
                for (int q = 0; q < NR; ++q) { cur[q][0] = nxt[q][0]; cur[q][1] = nxt[q][1]; }
            }
        }
    }
}

// Pass 2: one SINGLE-WAVE block per (box, pooled row, channel-quarter).
// slot j = blockIdx&7: quarter cq=j&3 runs only on XCDs {cq, cq+4}; each
// XCD's L2 working set is one 256-channel slice = 1.28 MB (L2-resident),
// and (new) that slice was PRODUCED on the same XCD pair by cvt.
__global__ __launch_bounds__(64) void roi_pool_bf16_kernel(
    const unsigned* __restrict__ ws,   // bf16 features (50,50,1024)
    const float* __restrict__ boxes,   // (300,4)
    float* __restrict__ out)           // (300,7,7,1024)
{
    const int j    = blockIdx.x & 7;           // XCD slot
    const int cq   = j & 3;                    // channel quarter -> XCD pair
    const int g    = blockIdx.x >> 3;          // [0, 1050)
    const int unit = g * 2 + (j >> 2);         // [0, 2100) = (box, pooled row)
    const int n    = unit / 7;                 // box 0..299
    const int py   = unit - n * 7;             // pooled row 0..6
    const int c    = cq * 64 + threadIdx.x;    // uint2 index in pixel, 0..255

    const float by1 = boxes[n * 4 + 0];
    const float bx1 = boxes[n * 4 + 1];
    const float by2 = boxes[n * 4 + 2];
    const float bx2 = boxes[n * 4 + 3];

    const float stepy = (by2 - by1) * (49.0f / 13.0f);
    const float stepx = (bx2 - bx1) * (49.0f / 13.0f);
    const float basey = by1 * 49.0f;
    const float basex = bx1 * 49.0f;

    const float ysA = basey + (float)(2 * py) * stepy;
    const float ysB = ysA + stepy;
    const float fA = floorf(ysA); const float wyA = ysA - fA;
    const float fB = floorf(ysB); const float wyB = ysB - fB;
    const int y0A = min(max((int)fA, 0), FH - 1); const int y1A = min(y0A + 1, FH - 1);
    const int y0B = min(max((int)fB, 0), FH - 1); const int y1B = min(y0B + 1, FH - 1);

    const uint2* __restrict__ f2 = reinterpret_cast<const uint2*>(ws);
    nat4* __restrict__ obase =
        reinterpret_cast<nat4*>(out) + (size_t)(n * (PO * PO) + py * PO) * FC4 + c;

    if (y0B == y0A) {              // 2 unique rows (also covers y-clamped edge)
        const int rows[2] = {y0A * FW, y1A * FW};
        pool_rows<2>(f2, rows, c, basex, stepx, wyA, wyB, obase);
    } else if (y0B == y1A) {       // 3 unique rows, middle shared
        const int rows[3] = {y0A * FW, y1A * FW, y1B * FW};
        pool_rows<3>(f2, rows, c, basex, stepx, wyA, wyB, obase);
    } else {                       // 4 unique rows
        const int rows[4] = {y0A * FW, y1A * FW, y0B * FW, y1B * FW};
        pool_rows<4>(f2, rows, c, basex, stepx, wyA, wyB, obase);
    }
}

// Fallback (ws too small): fp32 single-wave rolling-cache kernel (R6).
__global__ __launch_bounds__(64) void roi_pool_f32_kernel(
    const float* __restrict__ feat,
    const float* __restrict__ boxes,
    float* __restrict__ out)
{
    const int j = blockIdx.x & 7;
    const int k = blockIdx.x >> 3;
    const int n = j + 8 * (k / (PO * CHQ));
    if (n >= NBOX) return;
    const int r  = k % (PO * CHQ);
    const int py = r >> 2;
    const int cq = r & 3;
    const int c4 = cq * 64 + threadIdx.x;

    const float by1 = boxes[n * 4 + 0];
    const float bx1 = boxes[n * 4 + 1];
    const float by2 = boxes[n * 4 + 2];
    const float bx2 = boxes[n * 4 + 3];
    const float stepy = (by2 - by1) * (49.0f / 13.0f);
    const float stepx = (bx2 - bx1) * (49.0f / 13.0f);
    const float basey = by1 * 49.0f;
    const float basex = bx1 * 49.0f;
    const float ysA = basey + (float)(2 * py) * stepy;
    const float ysB = ysA + stepy;
    const float fA = floorf(ysA); const float wyA = ysA - fA;
    const float fB = floorf(ysB); const float wyB = ysB - fB;
    const int y0A = min(max((int)fA, 0), FH - 1); const int y1A = min(y0A + 1, FH - 1);
    const int y0B = min(max((int)fB, 0), FH - 1); const int y1B = min(y0B + 1, FH - 1);

    const nat4* __restrict__ f4 = reinterpret_cast<const nat4*>(feat);
    const int rA0 = y0A * FW, rA1 = y1A * FW, rB0 = y0B * FW, rB1 = y1B * FW;

    int cc = -1000;
    nat4 A00, A01, A10, A11, B00, B01, B10, B11;
    A00 = A01 = A10 = A11 = B00 = B01 = B10 = B11 = (nat4)0.0f;
    nat4 m = (nat4)(-INFINITY);
    nat4* __restrict__ obase =
        reinterpret_cast<nat4*>(out) + (size_t)(n * (PO * PO) + py * PO) * FC4 + c4;

    for (int ix = 0; ix < 2 * PO; ++ix) {
        const float xs = basex + (float)ix * stepx;
        const float xf = floorf(xs);
        const float wx = xs - xf;
        int x0 = min(max((int)xf, 0), FW - 1);
        const int x1 = min(x0 + 1, FW - 1);
        if (x0 != cc) {
            if (x0 == cc + 1) {
                A00 = A01; A10 = A11; B00 = B01; B10 = B11;
                A01 = f4[(rA0 + x1) * FC4 + c4];
                A11 = f4[(rA1 + x1) * FC4 + c4];
                B01 = f4[(rB0 + x1) * FC4 + c4];
                B11 = f4[(rB1 + x1) * FC4 + c4];
            } else {
                A00 = f4[(rA0 + x0) * FC4 + c4];
                A01 = f4[(rA0 + x1) * FC4 + c4];
                A10 = f4[(rA1 + x0) * FC4 + c4];
                A11 = f4[(rA1 + x1) * FC4 + c4];
                B00 = f4[(rB0 + x0) * FC4 + c4];
                B01 = f4[(rB0 + x1) * FC4 + c4];
                B10 = f4[(rB1 + x0) * FC4 + c4];
                B11 = f4[(rB1 + x1) * FC4 + c4];
            }
            cc = x0;
        }
        const nat4 vA = lerp4(lerp4(A00, A01, wx), lerp4(A10, A11, wx), wyA);
        const nat4 vB = lerp4(lerp4(B00, B01, wx), lerp4(B10, B11, wx), wyB);
        m = max4(m, max4(vA, vB));
        if (ix & 1) {
            __builtin_nontemporal_store(m, obase + (ix >> 1) * FC4);
            m = (nat4)(-INFINITY);
        }
    }
}

extern "C" void kernel_launch(void* const* d_in, const int* in_sizes, int n_in,
                              void* d_out, int out_size, void* d_ws, size_t ws_size,
                              hipStream_t stream) {
    (void)in_sizes; (void)n_in; (void)out_size;
    const float* feat  = (const float*)d_in[0];  // (1,50,50,1024)
    const float* boxes = (const float*)d_in[1];  // (1,300,4)
    float* out = (float*)d_out;                  // (1,300,7,7,1024)

    if (ws_size >= (size_t)BF16_BYTES) {
        unsigned* wsb = (unsigned*)d_ws;
        // 8 slots x 313 blocks; slot = (quarter, pixel-half), matching pool
        cvt_kernel<<<dim3(8 * 313), dim3(256), 0, stream>>>(feat, wsb);
        // 8 XCD slots x 1050 = 8400 single-wave blocks; cq = slot & 3
        roi_pool_bf16_kernel<<<dim3(8 * 1050), dim3(64), 0, stream>>>(wsb, boxes, out);
    } else {
        roi_pool_f32_kernel<<<dim3(8 * 38 * PO * CHQ), dim3(64), 0, stream>>>(feat, boxes, out);
    }
}